// Round 1
// baseline (190.976 us; speedup 1.0000x reference)
//
#include <hip/hip_runtime.h>
#include <math.h>

#define NB   32
#define CIN  4
#define COUT 64
#define TT   6
#define VV   512
#define P_OFF (NB*COUT*TT*VV)   // 6,291,456 floats: out then p in d_out

// ---------------------------------------------------------------------------
// Kernel 1: e_i[n,v], e_j[n,v]  (collapsed xc -> x1 -> e chain)
// e_i[n,v] = sum_{c,t} x[n,c,t,v] * l2w[t]*W1[c] + (sum_t l2w[t])*B1 + l2b*S1
// ---------------------------------------------------------------------------
__global__ __launch_bounds__(256) void e_kernel(
    const float* __restrict__ x,
    const float* __restrict__ conv_w,
    const float* __restrict__ conv_b,
    const float* __restrict__ l2_w,
    const float* __restrict__ l2_b,
    const float* __restrict__ l1_w,
    float* __restrict__ e)      // e[0..N*V) = e_i, e[N*V..2*N*V) = e_j
{
    __shared__ float W1[CIN], W2[CIN], cst[2];
    int tid = threadIdx.x;
    if (tid < CIN) {
        float w1 = 0.f, w2 = 0.f;
        for (int o = 0; o < COUT; ++o) {
            w1 += l1_w[o]        * conv_w[o*CIN + tid];
            w2 += l1_w[COUT + o] * conv_w[o*CIN + tid];
        }
        W1[tid] = w1; W2[tid] = w2;
    }
    if (tid == CIN) {
        float B1 = 0.f, B2 = 0.f, S1 = 0.f, S2 = 0.f;
        for (int o = 0; o < COUT; ++o) {
            B1 += l1_w[o]        * conv_b[o];
            B2 += l1_w[COUT + o] * conv_b[o];
            S1 += l1_w[o];
            S2 += l1_w[COUT + o];
        }
        float Ls = 0.f;
        for (int t = 0; t < TT; ++t) Ls += l2_w[t];
        cst[0] = Ls*B1 + l2_b[0]*S1;
        cst[1] = Ls*B2 + l2_b[0]*S2;
    }
    __syncthreads();

    int idx = blockIdx.x * 256 + tid;      // n*V + v
    int n = idx >> 9, v = idx & (VV-1);
    float ei = cst[0], ej = cst[1];
    #pragma unroll
    for (int c = 0; c < CIN; ++c) {
        float wc1 = W1[c], wc2 = W2[c];
        #pragma unroll
        for (int t = 0; t < TT; ++t) {
            float xv = x[((n*CIN + c)*TT + t)*VV + v];
            float lw = l2_w[t];
            ei += lw*wc1*xv;
            ej += lw*wc2*xv;
        }
    }
    e[idx]         = ei;
    e[NB*VV + idx] = ej;
}

// ---------------------------------------------------------------------------
// Kernel 2: masked leaky-relu softmax rows -> p (written into d_out p-region)
// One 64-lane wave per row (n,i); each lane handles 8 j's.
// ---------------------------------------------------------------------------
__global__ __launch_bounds__(256) void softmax_kernel(
    const int*   __restrict__ A,
    const float* __restrict__ e,
    const float* __restrict__ l1_b,
    float*       __restrict__ p)
{
    int wave = threadIdx.x >> 6;
    int lane = threadIdx.x & 63;
    int row  = blockIdx.x * 4 + wave;      // n*V + i
    int n = row >> 9, i = row & (VV-1);

    float bias = e[row] + l1_b[0];
    const int*   mrow = A + (((size_t)n*8 + 7)*VV + i)*VV;
    const float* ejp  = e + NB*VV + n*VV;

    int j0 = lane * 8;
    int4   m0 = *(const int4*)  (mrow + j0);
    int4   m1 = *(const int4*)  (mrow + j0 + 4);
    float4 f0 = *(const float4*)(ejp  + j0);
    float4 f1 = *(const float4*)(ejp  + j0 + 4);

    float s[8];
    int   mk[8] = {m0.x, m0.y, m0.z, m0.w, m1.x, m1.y, m1.z, m1.w};
    float ej[8] = {f0.x, f0.y, f0.z, f0.w, f1.x, f1.y, f1.z, f1.w};

    #pragma unroll
    for (int k = 0; k < 8; ++k) {
        float t = bias + ej[k];
        t = (t >= 0.f) ? t : 0.2f * t;
        s[k] = (mk[k] == 0) ? -INFINITY : t;
    }

    float m = -INFINITY;
    #pragma unroll
    for (int k = 0; k < 8; ++k) m = fmaxf(m, s[k]);
    #pragma unroll
    for (int off = 32; off; off >>= 1) m = fmaxf(m, __shfl_xor(m, off));

    float sum = 0.f;
    if (m > -INFINITY) {
        #pragma unroll
        for (int k = 0; k < 8; ++k) { s[k] = __expf(s[k] - m); sum += s[k]; }
    } else {
        #pragma unroll
        for (int k = 0; k < 8; ++k) s[k] = 0.f;
    }
    #pragma unroll
    for (int off = 32; off; off >>= 1) sum += __shfl_xor(sum, off);
    float inv = (sum > 0.f) ? 1.f / sum : 0.f;

    float* prow = p + ((size_t)n*VV + i)*VV + j0;
    float4 o0 = {s[0]*inv, s[1]*inv, s[2]*inv, s[3]*inv};
    float4 o1 = {s[4]*inv, s[5]*inv, s[6]*inv, s[7]*inv};
    *(float4*)(prow)     = o0;
    *(float4*)(prow + 4) = o1;
}

// ---------------------------------------------------------------------------
// Kernel 3: out[n,(o,t),w] = sum_v xc[n,o,t,v] * p[n,v,w]
// xc recomputed on the fly from x (L2-resident).
// Tile 64 rows x 64 cols, BK=32, 16x16 threads, 4x4 micro-tile.
// ---------------------------------------------------------------------------
__global__ __launch_bounds__(256) void out_kernel(
    const float* __restrict__ x,
    const float* __restrict__ conv_w,
    const float* __restrict__ conv_b,
    const float* __restrict__ p,
    float*       __restrict__ out)
{
    __shared__ float As[32][65];   // As[kk][r] = xc[n, rt*64+r, v0+kk]
    __shared__ float Bs[32][65];   // Bs[kk][w] = p[n, v0+kk, wt*64+w]

    int n  = blockIdx.z;
    int rt = blockIdx.y;           // 6 row tiles of 64 (rows = o*T+t, 384 total)
    int wt = blockIdx.x;           // 8 col tiles of 64
    int tid = threadIdx.x;
    int tx = tid & 15, ty = tid >> 4;

    const float* pn = p + (size_t)n*VV*VV + wt*64;
    float acc[4][4] = {};

    for (int v0 = 0; v0 < VV; v0 += 32) {
        // stage A-tile: consecutive lanes -> consecutive v (coalesced x reads)
        for (int l = tid; l < 64*32; l += 256) {
            int kk = l & 31, r = l >> 5;
            int R = rt*64 + r;
            int o = R / TT, t = R % TT;
            float xc = conv_b[o];
            #pragma unroll
            for (int c = 0; c < CIN; ++c)
                xc += x[((n*CIN + c)*TT + t)*VV + v0 + kk] * conv_w[o*CIN + c];
            As[kk][r] = xc;
        }
        // stage B-tile: consecutive lanes -> consecutive w (coalesced p reads)
        for (int l = tid; l < 32*64; l += 256) {
            int w = l & 63, kk = l >> 6;
            Bs[kk][w] = pn[(size_t)(v0 + kk)*VV + w];
        }
        __syncthreads();

        #pragma unroll
        for (int kk = 0; kk < 32; ++kk) {
            float a[4], b[4];
            #pragma unroll
            for (int i2 = 0; i2 < 4; ++i2) a[i2] = As[kk][ty*4 + i2];
            #pragma unroll
            for (int j2 = 0; j2 < 4; ++j2) b[j2] = Bs[kk][tx*4 + j2];
            #pragma unroll
            for (int i2 = 0; i2 < 4; ++i2)
                #pragma unroll
                for (int j2 = 0; j2 < 4; ++j2)
                    acc[i2][j2] += a[i2] * b[j2];
        }
        __syncthreads();
    }

    #pragma unroll
    for (int i2 = 0; i2 < 4; ++i2) {
        int R = rt*64 + ty*4 + i2;
        int o = R / TT, t = R % TT;
        float* orow = out + (((size_t)n*COUT + o)*TT + t)*VV + wt*64 + tx*4;
        float4 o4 = {acc[i2][0], acc[i2][1], acc[i2][2], acc[i2][3]};
        *(float4*)orow = o4;
    }
}

// ---------------------------------------------------------------------------
extern "C" void kernel_launch(void* const* d_in, const int* in_sizes, int n_in,
                              void* d_out, int out_size, void* d_ws, size_t ws_size,
                              hipStream_t stream)
{
    const float* x      = (const float*)d_in[0];
    const int*   A      = (const int*)  d_in[1];
    const float* conv_w = (const float*)d_in[2];
    const float* conv_b = (const float*)d_in[3];
    const float* l2_w   = (const float*)d_in[4];
    const float* l2_b   = (const float*)d_in[5];
    const float* l1_w   = (const float*)d_in[6];
    const float* l1_b   = (const float*)d_in[7];

    float* out = (float*)d_out;
    float* pP  = out + P_OFF;          // p lives in its d_out slot
    float* e   = (float*)d_ws;         // 2 * N*V floats = 128 KB

    // 1) e_i / e_j
    e_kernel<<<NB*VV/256, 256, 0, stream>>>(x, conv_w, conv_b, l2_w, l2_b, l1_w, e);
    // 2) masked softmax -> p
    softmax_kernel<<<NB*VV/4, 256, 0, stream>>>(A, e, l1_b, pP);
    // 3) out = xc @ p
    dim3 g3(8, 6, NB);
    out_kernel<<<g3, 256, 0, stream>>>(x, conv_w, conv_b, pP, out);
}

// Round 2
// 89.308 us; speedup vs baseline: 2.1384x; 2.1384x over previous
//
#include <hip/hip_runtime.h>
#include <math.h>

#define NB   32
#define CIN  4
#define COUT 64
#define TT   6
#define VV   512
#define P_OFF (NB*COUT*TT*VV)   // out then p in d_out
#define SPLITS 8
#define VCHUNK (VV/SPLITS)      // 64
#define NROW 24                 // c*6+t rows of x per batch
#define E_FLOATS (2*NB*VV)      // e_i + e_j in ws

// ---------------------------------------------------------------------------
// Kernel 1: e_i[n,v], e_j[n,v]  (collapsed xc -> x1 -> e chain)
// ---------------------------------------------------------------------------
__global__ __launch_bounds__(256) void e_kernel(
    const float* __restrict__ x,
    const float* __restrict__ conv_w,
    const float* __restrict__ conv_b,
    const float* __restrict__ l2_w,
    const float* __restrict__ l2_b,
    const float* __restrict__ l1_w,
    float* __restrict__ e)
{
    __shared__ float W1[CIN], W2[CIN], cst[2];
    int tid = threadIdx.x;
    if (tid < CIN) {
        float w1 = 0.f, w2 = 0.f;
        for (int o = 0; o < COUT; ++o) {
            w1 += l1_w[o]        * conv_w[o*CIN + tid];
            w2 += l1_w[COUT + o] * conv_w[o*CIN + tid];
        }
        W1[tid] = w1; W2[tid] = w2;
    }
    if (tid == CIN) {
        float B1 = 0.f, B2 = 0.f, S1 = 0.f, S2 = 0.f;
        for (int o = 0; o < COUT; ++o) {
            B1 += l1_w[o]        * conv_b[o];
            B2 += l1_w[COUT + o] * conv_b[o];
            S1 += l1_w[o];
            S2 += l1_w[COUT + o];
        }
        float Ls = 0.f;
        for (int t = 0; t < TT; ++t) Ls += l2_w[t];
        cst[0] = Ls*B1 + l2_b[0]*S1;
        cst[1] = Ls*B2 + l2_b[0]*S2;
    }
    __syncthreads();

    int idx = blockIdx.x * 256 + tid;      // n*V + v
    int n = idx >> 9, v = idx & (VV-1);
    float ei = cst[0], ej = cst[1];
    #pragma unroll
    for (int c = 0; c < CIN; ++c) {
        float wc1 = W1[c], wc2 = W2[c];
        #pragma unroll
        for (int t = 0; t < TT; ++t) {
            float xv = x[((n*CIN + c)*TT + t)*VV + v];
            float lw = l2_w[t];
            ei += lw*wc1*xv;
            ej += lw*wc2*xv;
        }
    }
    e[idx]         = ei;
    e[NB*VV + idx] = ej;
}

// ---------------------------------------------------------------------------
// Kernel 2: masked leaky-relu softmax rows -> p (f32, into d_out p-region)
// ---------------------------------------------------------------------------
__global__ __launch_bounds__(256) void softmax_kernel(
    const int*   __restrict__ A,
    const float* __restrict__ e,
    const float* __restrict__ l1_b,
    float*       __restrict__ p)
{
    int wave = threadIdx.x >> 6;
    int lane = threadIdx.x & 63;
    int row  = blockIdx.x * 4 + wave;      // n*V + i
    int n = row >> 9, i = row & (VV-1);

    float bias = e[row] + l1_b[0];
    const int*   mrow = A + (((size_t)n*8 + 7)*VV + i)*VV;
    const float* ejp  = e + NB*VV + n*VV;

    int j0 = lane * 8;
    int4   m0 = *(const int4*)  (mrow + j0);
    int4   m1 = *(const int4*)  (mrow + j0 + 4);
    float4 f0 = *(const float4*)(ejp  + j0);
    float4 f1 = *(const float4*)(ejp  + j0 + 4);

    float s[8];
    int   mk[8] = {m0.x, m0.y, m0.z, m0.w, m1.x, m1.y, m1.z, m1.w};
    float ej[8] = {f0.x, f0.y, f0.z, f0.w, f1.x, f1.y, f1.z, f1.w};

    #pragma unroll
    for (int k = 0; k < 8; ++k) {
        float t = bias + ej[k];
        t = (t >= 0.f) ? t : 0.2f * t;
        s[k] = (mk[k] == 0) ? -INFINITY : t;
    }

    float m = -INFINITY;
    #pragma unroll
    for (int k = 0; k < 8; ++k) m = fmaxf(m, s[k]);
    #pragma unroll
    for (int off = 32; off; off >>= 1) m = fmaxf(m, __shfl_xor(m, off));

    float sum = 0.f;
    if (m > -INFINITY) {
        #pragma unroll
        for (int k = 0; k < 8; ++k) { s[k] = __expf(s[k] - m); sum += s[k]; }
    } else {
        #pragma unroll
        for (int k = 0; k < 8; ++k) s[k] = 0.f;
    }
    #pragma unroll
    for (int off = 32; off; off >>= 1) sum += __shfl_xor(sum, off);
    float inv = (sum > 0.f) ? 1.f / sum : 0.f;

    float* prow = p + ((size_t)n*VV + i)*VV + j0;
    float4 o0 = {s[0]*inv, s[1]*inv, s[2]*inv, s[3]*inv};
    float4 o1 = {s[4]*inv, s[5]*inv, s[6]*inv, s[7]*inv};
    *(float4*)(prow)     = o0;
    *(float4*)(prow + 4) = o1;
}

// ---------------------------------------------------------------------------
// Kernel 3: y_part[s][n][r][w] = sum_{v in chunk s} x[n,r,v] * p[n,v,w]
//           row 24 = colsum of p chunk. r = c*6+t (x[n] is contiguous [24][512]).
// One thread per w; x-slab staged in LDS, read as uniform (broadcast) float4.
// ---------------------------------------------------------------------------
__global__ __launch_bounds__(256) void y_kernel(
    const float* __restrict__ x,
    const float* __restrict__ p,
    float*       __restrict__ ypart)
{
    __shared__ float xs[NROW][VCHUNK];   // 6 KB
    int s  = blockIdx.x;                 // v-chunk
    int wt = blockIdx.y;                 // 0..1
    int n  = blockIdx.z;
    int tid = threadIdx.x;
    int w = wt*256 + tid;

    for (int l = tid; l < NROW*VCHUNK; l += 256) {
        int r = l / VCHUNK, v = l % VCHUNK;
        xs[r][v] = x[((size_t)n*NROW + r)*VV + s*VCHUNK + v];
    }
    __syncthreads();

    float acc[NROW+1];
    #pragma unroll
    for (int r = 0; r <= NROW; ++r) acc[r] = 0.f;

    const float* pn = p + ((size_t)n*VV + s*VCHUNK)*VV + w;

    float4 pv;
    pv.x = pn[0*VV]; pv.y = pn[1*VV]; pv.z = pn[2*VV]; pv.w = pn[3*VV];

    for (int v4 = 0; v4 < VCHUNK/4; ++v4) {
        float4 cur = pv;
        if (v4 + 1 < VCHUNK/4) {
            const float* pnx = pn + (size_t)(v4+1)*4*VV;
            pv.x = pnx[0]; pv.y = pnx[VV]; pv.z = pnx[2*VV]; pv.w = pnx[3*VV];
        }
        #pragma unroll
        for (int r = 0; r < NROW; ++r) {
            float4 xr = *(const float4*)&xs[r][v4*4];
            acc[r] += xr.x*cur.x + xr.y*cur.y + xr.z*cur.z + xr.w*cur.w;
        }
        acc[NROW] += cur.x + cur.y + cur.z + cur.w;
    }

    float* yo = ypart + (((size_t)s*NB + n)*(NROW+1))*VV + w;
    #pragma unroll
    for (int r = 0; r <= NROW; ++r) yo[(size_t)r*VV] = acc[r];
}

// ---------------------------------------------------------------------------
// Kernel 4: out[n,o,t,w] = sum_c conv_w[o,c]*y[c*6+t,w] + conv_b[o]*y[24,w]
//           (y = sum over SPLITS partials)
// ---------------------------------------------------------------------------
__global__ __launch_bounds__(256) void expand_kernel(
    const float* __restrict__ ypart,
    const float* __restrict__ conv_w,
    const float* __restrict__ conv_b,
    float*       __restrict__ out)
{
    __shared__ float wsm[COUT*CIN];
    __shared__ float bsm[COUT];
    int tid = threadIdx.x;
    if (tid < COUT*CIN) wsm[tid] = conv_w[tid];
    if (tid < COUT)     bsm[tid] = conv_b[tid];
    __syncthreads();

    int og = blockIdx.x;                 // o-group of 16
    int wt = blockIdx.y;
    int n  = blockIdx.z;
    int w = wt*256 + tid;

    float y[NROW+1];
    #pragma unroll
    for (int r = 0; r <= NROW; ++r) {
        float a = 0.f;
        #pragma unroll
        for (int s = 0; s < SPLITS; ++s)
            a += ypart[(((size_t)s*NB + n)*(NROW+1) + r)*VV + w];
        y[r] = a;
    }

    for (int oo = 0; oo < 16; ++oo) {
        int o = og*16 + oo;
        float wb[CIN];
        #pragma unroll
        for (int c = 0; c < CIN; ++c) wb[c] = wsm[o*CIN + c];
        float bo = bsm[o];
        #pragma unroll
        for (int t = 0; t < TT; ++t) {
            float val = bo * y[NROW];
            #pragma unroll
            for (int c = 0; c < CIN; ++c) val += wb[c] * y[c*TT + t];
            out[(((size_t)n*COUT + o)*TT + t)*VV + w] = val;
        }
    }
}

// ---------------------------------------------------------------------------
extern "C" void kernel_launch(void* const* d_in, const int* in_sizes, int n_in,
                              void* d_out, int out_size, void* d_ws, size_t ws_size,
                              hipStream_t stream)
{
    const float* x      = (const float*)d_in[0];
    const int*   A      = (const int*)  d_in[1];
    const float* conv_w = (const float*)d_in[2];
    const float* conv_b = (const float*)d_in[3];
    const float* l2_w   = (const float*)d_in[4];
    const float* l2_b   = (const float*)d_in[5];
    const float* l1_w   = (const float*)d_in[6];
    const float* l1_b   = (const float*)d_in[7];

    float* out = (float*)d_out;
    float* pP  = out + P_OFF;              // p region of d_out
    float* e   = (float*)d_ws;             // 128 KB
    float* yp  = e + E_FLOATS;             // SPLITS*NB*25*VV f32 = 13.1 MB

    e_kernel<<<NB*VV/256, 256, 0, stream>>>(x, conv_w, conv_b, l2_w, l2_b, l1_w, e);
    softmax_kernel<<<NB*VV/4, 256, 0, stream>>>(A, e, l1_b, pP);

    dim3 gy(SPLITS, 2, NB);                // 512 blocks
    y_kernel<<<gy, 256, 0, stream>>>(x, pP, yp);

    dim3 ge(4, 2, NB);                     // 256 blocks
    expand_kernel<<<ge, 256, 0, stream>>>(yp, conv_w, conv_b, out);
}

// Round 3
// 55.572 us; speedup vs baseline: 3.4365x; 1.6071x over previous
//
#include <hip/hip_runtime.h>
#include <math.h>

#define NB   32
#define CIN  4
#define COUT 64
#define TT   6
#define VV   512
#define P_OFF (NB*COUT*TT*VV)   // out then p in d_out
#define SPLITS 4
#define NROW 24                 // c*6+t rows of x per batch
#define E_FLOATS (2*NB*VV)      // e_i + e_j in ws

// ---------------------------------------------------------------------------
// Kernel 1: e_i[n,v], e_j[n,v]  (collapsed xc -> x1 -> e chain)
// ---------------------------------------------------------------------------
__global__ __launch_bounds__(256) void e_kernel(
    const float* __restrict__ x,
    const float* __restrict__ conv_w,
    const float* __restrict__ conv_b,
    const float* __restrict__ l2_w,
    const float* __restrict__ l2_b,
    const float* __restrict__ l1_w,
    float* __restrict__ e)
{
    __shared__ float W1[CIN], W2[CIN], cst[2];
    int tid = threadIdx.x;
    if (tid < CIN) {
        float w1 = 0.f, w2 = 0.f;
        for (int o = 0; o < COUT; ++o) {
            w1 += l1_w[o]        * conv_w[o*CIN + tid];
            w2 += l1_w[COUT + o] * conv_w[o*CIN + tid];
        }
        W1[tid] = w1; W2[tid] = w2;
    }
    if (tid == CIN) {
        float B1 = 0.f, B2 = 0.f, S1 = 0.f, S2 = 0.f;
        for (int o = 0; o < COUT; ++o) {
            B1 += l1_w[o]        * conv_b[o];
            B2 += l1_w[COUT + o] * conv_b[o];
            S1 += l1_w[o];
            S2 += l1_w[COUT + o];
        }
        float Ls = 0.f;
        for (int t = 0; t < TT; ++t) Ls += l2_w[t];
        cst[0] = Ls*B1 + l2_b[0]*S1;
        cst[1] = Ls*B2 + l2_b[0]*S2;
    }
    __syncthreads();

    int idx = blockIdx.x * 256 + tid;      // n*V + v
    int n = idx >> 9, v = idx & (VV-1);
    float ei = cst[0], ej = cst[1];
    #pragma unroll
    for (int c = 0; c < CIN; ++c) {
        float wc1 = W1[c], wc2 = W2[c];
        #pragma unroll
        for (int t = 0; t < TT; ++t) {
            float xv = x[((n*CIN + c)*TT + t)*VV + v];
            float lw = l2_w[t];
            ei += lw*wc1*xv;
            ej += lw*wc2*xv;
        }
    }
    e[idx]         = ei;
    e[NB*VV + idx] = ej;
}

// ---------------------------------------------------------------------------
// Kernel 2: masked leaky-relu softmax rows -> p (f32, into d_out p-region)
// ---------------------------------------------------------------------------
__global__ __launch_bounds__(256) void softmax_kernel(
    const int*   __restrict__ A,
    const float* __restrict__ e,
    const float* __restrict__ l1_b,
    float*       __restrict__ p)
{
    int wave = threadIdx.x >> 6;
    int lane = threadIdx.x & 63;
    int row  = blockIdx.x * 4 + wave;      // n*V + i
    int n = row >> 9, i = row & (VV-1);

    float bias = e[row] + l1_b[0];
    const int*   mrow = A + (((size_t)n*8 + 7)*VV + i)*VV;
    const float* ejp  = e + NB*VV + n*VV;

    int j0 = lane * 8;
    int4   m0 = *(const int4*)  (mrow + j0);
    int4   m1 = *(const int4*)  (mrow + j0 + 4);
    float4 f0 = *(const float4*)(ejp  + j0);
    float4 f1 = *(const float4*)(ejp  + j0 + 4);

    float s[8];
    int   mk[8] = {m0.x, m0.y, m0.z, m0.w, m1.x, m1.y, m1.z, m1.w};
    float ej[8] = {f0.x, f0.y, f0.z, f0.w, f1.x, f1.y, f1.z, f1.w};

    #pragma unroll
    for (int k = 0; k < 8; ++k) {
        float t = bias + ej[k];
        t = (t >= 0.f) ? t : 0.2f * t;
        s[k] = (mk[k] == 0) ? -INFINITY : t;
    }

    float m = -INFINITY;
    #pragma unroll
    for (int k = 0; k < 8; ++k) m = fmaxf(m, s[k]);
    #pragma unroll
    for (int off = 32; off; off >>= 1) m = fmaxf(m, __shfl_xor(m, off));

    float sum = 0.f;
    if (m > -INFINITY) {
        #pragma unroll
        for (int k = 0; k < 8; ++k) { s[k] = __expf(s[k] - m); sum += s[k]; }
    } else {
        #pragma unroll
        for (int k = 0; k < 8; ++k) s[k] = 0.f;
    }
    #pragma unroll
    for (int off = 32; off; off >>= 1) sum += __shfl_xor(sum, off);
    float inv = (sum > 0.f) ? 1.f / sum : 0.f;

    float* prow = p + ((size_t)n*VV + i)*VV + j0;
    float4 o0 = {s[0]*inv, s[1]*inv, s[2]*inv, s[3]*inv};
    float4 o1 = {s[4]*inv, s[5]*inv, s[6]*inv, s[7]*inv};
    *(float4*)(prow)     = o0;
    *(float4*)(prow + 4) = o1;
}

// ---------------------------------------------------------------------------
// Kernel 3: y_part[s][n][r][w] = sum_{v in 128-chunk s} x[n,r,v] * p[n,v,w]
// row 24 = colsum. p tile staged in LDS (coalesced float4), x slab in LDS.
// 256 thr: wave = v-group (4 x 16 v per 64-subtile), lane = w-pair (2 w).
// ---------------------------------------------------------------------------
__global__ __launch_bounds__(256) void y_kernel(
    const float* __restrict__ x,
    const float* __restrict__ p,
    float*       __restrict__ ypart)
{
    __shared__ union {
        struct { float xs[NROW][128]; float ps[64][128]; } t;   // 12 + 32 KB
        float red[3][NROW+1][128];                              // 38.4 KB
    } sm;

    int s  = blockIdx.x;     // 4 v-chunks of 128
    int wt = blockIdx.y;     // 4 w-chunks of 128
    int n  = blockIdx.z;
    int tid = threadIdx.x;
    int wp = tid & 63;       // w-pair: w = wp*2, wp*2+1
    int vg = tid >> 6;       // wave id = v-subgroup

    for (int l = tid; l < NROW*128; l += 256) {
        int r = l >> 7, v = l & 127;
        sm.t.xs[r][v] = x[((size_t)n*NROW + r)*VV + s*128 + v];
    }

    float acc[NROW+1][2];
    #pragma unroll
    for (int r = 0; r <= NROW; ++r) { acc[r][0] = 0.f; acc[r][1] = 0.f; }

    for (int sub = 0; sub < 2; ++sub) {
        __syncthreads();
        for (int l = tid; l < 64*32; l += 256) {
            int row = l >> 5, c4 = l & 31;
            float4 v4 = *(const float4*)(p +
                ((size_t)(n*VV + s*128 + sub*64 + row))*VV + wt*128 + c4*4);
            *(float4*)&sm.t.ps[row][c4*4] = v4;
        }
        __syncthreads();

        #pragma unroll
        for (int i = 0; i < 16; i += 4) {
            float2 pv[4];
            #pragma unroll
            for (int q = 0; q < 4; ++q)
                pv[q] = *(const float2*)&sm.t.ps[vg*16 + i + q][wp*2];
            #pragma unroll
            for (int r = 0; r < NROW; ++r) {
                float4 xv = *(const float4*)&sm.t.xs[r][sub*64 + vg*16 + i];
                acc[r][0] = fmaf(xv.x, pv[0].x, acc[r][0]);
                acc[r][1] = fmaf(xv.x, pv[0].y, acc[r][1]);
                acc[r][0] = fmaf(xv.y, pv[1].x, acc[r][0]);
                acc[r][1] = fmaf(xv.y, pv[1].y, acc[r][1]);
                acc[r][0] = fmaf(xv.z, pv[2].x, acc[r][0]);
                acc[r][1] = fmaf(xv.z, pv[2].y, acc[r][1]);
                acc[r][0] = fmaf(xv.w, pv[3].x, acc[r][0]);
                acc[r][1] = fmaf(xv.w, pv[3].y, acc[r][1]);
            }
            #pragma unroll
            for (int q = 0; q < 4; ++q) {
                acc[NROW][0] += pv[q].x;
                acc[NROW][1] += pv[q].y;
            }
        }
    }

    __syncthreads();
    if (vg > 0) {
        #pragma unroll
        for (int r = 0; r <= NROW; ++r) {
            sm.red[vg-1][r][wp*2]   = acc[r][0];
            sm.red[vg-1][r][wp*2+1] = acc[r][1];
        }
    }
    __syncthreads();
    if (vg == 0) {
        float* yo = ypart + ((size_t)(s*NB + n)*(NROW+1))*VV + wt*128 + wp*2;
        #pragma unroll
        for (int r = 0; r <= NROW; ++r) {
            float a0 = acc[r][0], a1 = acc[r][1];
            #pragma unroll
            for (int g = 0; g < 3; ++g) {
                a0 += sm.red[g][r][wp*2];
                a1 += sm.red[g][r][wp*2+1];
            }
            float2 st = {a0, a1};
            *(float2*)(yo + (size_t)r*VV) = st;
        }
    }
}

// ---------------------------------------------------------------------------
// Kernel 4: out[n,o,t,w] = sum_c conv_w[o,c]*y[c*6+t,w] + conv_b[o]*y[24,w]
// Split-reduction inlined; 1024 blocks (4 o's each).
// ---------------------------------------------------------------------------
__global__ __launch_bounds__(256) void expand_kernel(
    const float* __restrict__ ypart,
    const float* __restrict__ conv_w,
    const float* __restrict__ conv_b,
    float*       __restrict__ out)
{
    __shared__ float wsm[COUT*CIN];
    __shared__ float bsm[COUT];
    int tid = threadIdx.x;
    if (tid < COUT*CIN) wsm[tid] = conv_w[tid];
    if (tid < COUT)     bsm[tid] = conv_b[tid];
    __syncthreads();

    int og = blockIdx.x;                 // 16 groups of 4 o
    int wt = blockIdx.y;                 // 2
    int n  = blockIdx.z;
    int w = wt*256 + tid;

    float y[NROW+1];
    #pragma unroll
    for (int r = 0; r <= NROW; ++r) {
        float a = 0.f;
        #pragma unroll
        for (int s = 0; s < SPLITS; ++s)
            a += ypart[((size_t)(s*NB + n)*(NROW+1) + r)*VV + w];
        y[r] = a;
    }

    #pragma unroll
    for (int oo = 0; oo < 4; ++oo) {
        int o = og*4 + oo;
        float wb[CIN];
        #pragma unroll
        for (int c = 0; c < CIN; ++c) wb[c] = wsm[o*CIN + c];
        float bo = bsm[o];
        #pragma unroll
        for (int t = 0; t < TT; ++t) {
            float val = bo * y[NROW];
            #pragma unroll
            for (int c = 0; c < CIN; ++c) val += wb[c] * y[c*TT + t];
            out[(((size_t)n*COUT + o)*TT + t)*VV + w] = val;
        }
    }
}

// ---------------------------------------------------------------------------
extern "C" void kernel_launch(void* const* d_in, const int* in_sizes, int n_in,
                              void* d_out, int out_size, void* d_ws, size_t ws_size,
                              hipStream_t stream)
{
    const float* x      = (const float*)d_in[0];
    const int*   A      = (const int*)  d_in[1];
    const float* conv_w = (const float*)d_in[2];
    const float* conv_b = (const float*)d_in[3];
    const float* l2_w   = (const float*)d_in[4];
    const float* l2_b   = (const float*)d_in[5];
    const float* l1_w   = (const float*)d_in[6];
    const float* l1_b   = (const float*)d_in[7];

    float* out = (float*)d_out;
    float* pP  = out + P_OFF;              // p region of d_out
    float* e   = (float*)d_ws;             // 128 KB
    float* yp  = e + E_FLOATS;             // SPLITS*NB*25*VV f32 = 6.55 MB

    e_kernel<<<NB*VV/256, 256, 0, stream>>>(x, conv_w, conv_b, l2_w, l2_b, l1_w, e);
    softmax_kernel<<<NB*VV/4, 256, 0, stream>>>(A, e, l1_b, pP);

    dim3 gy(SPLITS, 4, NB);                // 512 blocks
    y_kernel<<<gy, 256, 0, stream>>>(x, pP, yp);

    dim3 ge(16, 2, NB);                    // 1024 blocks
    expand_kernel<<<ge, 256, 0, stream>>>(yp, conv_w, conv_b, out);
}